// Round 4
// baseline (579.290 us; speedup 1.0000x reference)
//
#include <hip/hip_runtime.h>

#define NROWS 65536
#define KCODES 1024
#define DDIM 256

// output offsets in floats (concat of reference return tuple)
#define Q_OFF    0
#define LOSS_OFF 16777216
#define PERP_OFF 16777217
#define IND_OFF  16777218
#define DIST_OFF 16842754

#define MARGIN  4e-4f
#define MAXCAND 16
#define RG_BLOCKS (NROWS / 4)

typedef unsigned long long u64;
typedef unsigned int u32;
typedef unsigned short u16;
typedef __attribute__((ext_vector_type(8))) short bf16x8;
typedef __attribute__((ext_vector_type(4))) float f32x4;

// RNE float->bf16 bits (no NaN handling; inputs are tame)
__device__ inline u32 f2bf_bits(float f) {
    u32 u = __float_as_uint(f);
    return (u + 0x7fffu + ((u >> 16) & 1u)) >> 16;
}
__device__ inline float bf2f(u32 bits) { return __uint_as_float(bits << 16); }

// ---------------- init workspace ----------------------------------------------
__global__ __launch_bounds__(256) void init_kernel(u32* __restrict__ cand_cnt,
                                                   u32* __restrict__ hist) {
    int i = blockIdx.x * 256 + threadIdx.x;
    if (i < NROWS) cand_cnt[i] = 0u;
    if (i < KCODES) hist[i] = 0u;
}

// ---------------- squared norms (fp32, epilogue + refine both reuse these) ----
__global__ __launch_bounds__(256) void sqnorm_kernel(
    const float* __restrict__ lat, const float* __restrict__ emb,
    float* __restrict__ row_sq, float* __restrict__ emb_sq) {
    int gwave = (blockIdx.x * 256 + threadIdx.x) >> 6;
    int lane = threadIdx.x & 63;
    if (gwave >= NROWS + KCODES) return;
    const float* src = (gwave < NROWS) ? lat + (size_t)gwave * DDIM
                                       : emb + (size_t)(gwave - NROWS) * DDIM;
    float4 v = *reinterpret_cast<const float4*>(src + lane * 4);
    float s = v.x * v.x + v.y * v.y + v.z * v.z + v.w * v.w;
#pragma unroll
    for (int m = 32; m >= 1; m >>= 1) s += __shfl_xor(s, m, 64);
    if (lane == 0) {
        if (gwave < NROWS) row_sq[gwave] = s;
        else emb_sq[gwave - NROWS] = s;
    }
}

// ---------------- dist via bf16-split MFMA (3 products: hh + hl + lh) ---------
// 128x128 tile, 4 waves, BK=32. Pruner only: exact argmin refined later.
__global__ __launch_bounds__(256, 2) void dist_mfma_kernel(
    const float* __restrict__ A, const float* __restrict__ B,
    const float* __restrict__ row_sq, const float* __restrict__ emb_sq,
    float* __restrict__ dist, u32* __restrict__ cand_cnt, u16* __restrict__ cand) {
    __shared__ u16 Ah[128 * 40], Al[128 * 40], Bh[128 * 40], Bl[128 * 40];
    const int tid = threadIdx.x;
    const int lane = tid & 63, wid = tid >> 6;
    const int wr = wid >> 1, wc = wid & 1;       // wave quadrant (64x64)
    const int li = lane & 15, lg = lane >> 4;
    const int row0 = blockIdx.y * 128, col0 = blockIdx.x * 128;
    const int rbase = tid >> 3, c4 = tid & 7;    // staging: chunk row/slot

    f32x4 acc[4][4];
#pragma unroll
    for (int mf = 0; mf < 4; ++mf)
#pragma unroll
        for (int nf = 0; nf < 4; ++nf) acc[mf][nf] = (f32x4)0.0f;

    // prefetch K-step 0 into registers
    float4 ra[4], rb[4];
#pragma unroll
    for (int i = 0; i < 4; ++i) {
        int r = rbase + i * 32;
        ra[i] = *reinterpret_cast<const float4*>(A + (size_t)(row0 + r) * DDIM + c4 * 4);
        rb[i] = *reinterpret_cast<const float4*>(B + (size_t)(col0 + r) * DDIM + c4 * 4);
    }

    for (int ks = 0; ks < 8; ++ks) {
        __syncthreads();  // previous iter's LDS reads done
        // convert + write staged registers to LDS (hi/lo bf16 pairs)
#pragma unroll
        for (int i = 0; i < 4; ++i) {
            int r = rbase + i * 32;
            float av[4] = {ra[i].x, ra[i].y, ra[i].z, ra[i].w};
            float bv[4] = {rb[i].x, rb[i].y, rb[i].z, rb[i].w};
            u32 ahb[4], alb[4], bhb[4], blb[4];
#pragma unroll
            for (int j = 0; j < 4; ++j) {
                ahb[j] = f2bf_bits(av[j]);
                alb[j] = f2bf_bits(av[j] - bf2f(ahb[j]));
                bhb[j] = f2bf_bits(bv[j]);
                blb[j] = f2bf_bits(bv[j] - bf2f(bhb[j]));
            }
            int o = r * 40 + c4 * 4;
            *reinterpret_cast<uint2*>(&Ah[o]) = make_uint2(ahb[0] | (ahb[1] << 16), ahb[2] | (ahb[3] << 16));
            *reinterpret_cast<uint2*>(&Al[o]) = make_uint2(alb[0] | (alb[1] << 16), alb[2] | (alb[3] << 16));
            *reinterpret_cast<uint2*>(&Bh[o]) = make_uint2(bhb[0] | (bhb[1] << 16), bhb[2] | (bhb[3] << 16));
            *reinterpret_cast<uint2*>(&Bl[o]) = make_uint2(blb[0] | (blb[1] << 16), blb[2] | (blb[3] << 16));
        }
        // issue next K-step's global loads (fly under MFMA)
        if (ks < 7) {
            int d0 = (ks + 1) * 32;
#pragma unroll
            for (int i = 0; i < 4; ++i) {
                int r = rbase + i * 32;
                ra[i] = *reinterpret_cast<const float4*>(A + (size_t)(row0 + r) * DDIM + d0 + c4 * 4);
                rb[i] = *reinterpret_cast<const float4*>(B + (size_t)(col0 + r) * DDIM + d0 + c4 * 4);
            }
        }
        __syncthreads();
        // fragment reads: A row = li, k = lg*8 + 0..7
        bf16x8 fah[4], fal[4], fbh[4], fbl[4];
        int k0 = lg * 8;
#pragma unroll
        for (int mf = 0; mf < 4; ++mf) {
            int r = wr * 64 + mf * 16 + li;
            fah[mf] = *reinterpret_cast<const bf16x8*>(&Ah[r * 40 + k0]);
            fal[mf] = *reinterpret_cast<const bf16x8*>(&Al[r * 40 + k0]);
        }
#pragma unroll
        for (int nf = 0; nf < 4; ++nf) {
            int c = wc * 64 + nf * 16 + li;
            fbh[nf] = *reinterpret_cast<const bf16x8*>(&Bh[c * 40 + k0]);
            fbl[nf] = *reinterpret_cast<const bf16x8*>(&Bl[c * 40 + k0]);
        }
#pragma unroll
        for (int mf = 0; mf < 4; ++mf)
#pragma unroll
            for (int nf = 0; nf < 4; ++nf) {
                acc[mf][nf] = __builtin_amdgcn_mfma_f32_16x16x32_bf16(fah[mf], fbh[nf], acc[mf][nf], 0, 0, 0);
                acc[mf][nf] = __builtin_amdgcn_mfma_f32_16x16x32_bf16(fah[mf], fbl[nf], acc[mf][nf], 0, 0, 0);
                acc[mf][nf] = __builtin_amdgcn_mfma_f32_16x16x32_bf16(fal[mf], fbh[nf], acc[mf][nf], 0, 0, 0);
            }
    }

    // ---------------- epilogue: dist write + block-local row-min + candidates --
    __syncthreads();
    float* rs_lds = reinterpret_cast<float*>(Ah);      // 128 f
    float* es_lds = rs_lds + 128;                      // 128 f
    float* rowmin_lds = es_lds + 128;                  // 128 f
    if (tid < 128) rs_lds[tid] = row_sq[row0 + tid];
    else if (tid < 256) es_lds[tid - 128] = emb_sq[col0 + tid - 128];
    __syncthreads();

    // C/D layout: row = (lane>>4)*4 + reg, col = lane&15 (per 16x16 frag)
    float rmin[16];
#pragma unroll
    for (int mf = 0; mf < 4; ++mf)
#pragma unroll
        for (int rg = 0; rg < 4; ++rg) {
            int rl = wr * 64 + mf * 16 + lg * 4 + rg;
            float rs = rs_lds[rl];
            float best = 3.4e38f;
#pragma unroll
            for (int nf = 0; nf < 4; ++nf) {
                int cl = wc * 64 + nf * 16 + li;
                float dv = (rs + es_lds[cl]) - 2.0f * acc[mf][nf][rg];
                dist[(size_t)(row0 + rl) * KCODES + col0 + cl] = dv;
                best = fminf(best, dv);
            }
            rmin[mf * 4 + rg] = best;
        }
    // reduce row-min across the 16 lanes (li bits)
#pragma unroll
    for (int m = 8; m >= 1; m >>= 1)
#pragma unroll
        for (int j = 0; j < 16; ++j) rmin[j] = fminf(rmin[j], __shfl_xor(rmin[j], m, 64));
    // combine across the two wc waves via LDS
    if (wc == 0 && li == 0) {
#pragma unroll
        for (int mf = 0; mf < 4; ++mf)
#pragma unroll
            for (int rg = 0; rg < 4; ++rg)
                rowmin_lds[wr * 64 + mf * 16 + lg * 4 + rg] = rmin[mf * 4 + rg];
    }
    __syncthreads();
    if (wc == 1 && li == 0) {
#pragma unroll
        for (int mf = 0; mf < 4; ++mf)
#pragma unroll
            for (int rg = 0; rg < 4; ++rg) {
                int rl = wr * 64 + mf * 16 + lg * 4 + rg;
                rowmin_lds[rl] = fminf(rowmin_lds[rl], rmin[mf * 4 + rg]);
            }
    }
    __syncthreads();
    // candidate recording: dv <= block-row-min + MARGIN (superset of all
    // fp32-min achievers; see containment bound in journal)
#pragma unroll
    for (int mf = 0; mf < 4; ++mf)
#pragma unroll
        for (int rg = 0; rg < 4; ++rg) {
            int rl = wr * 64 + mf * 16 + lg * 4 + rg;
            float thr = rowmin_lds[rl] + MARGIN;
            float rs = rs_lds[rl];
#pragma unroll
            for (int nf = 0; nf < 4; ++nf) {
                int cl = wc * 64 + nf * 16 + li;
                float dv = (rs + es_lds[cl]) - 2.0f * acc[mf][nf][rg];
                if (dv <= thr) {
                    int grow = row0 + rl;
                    u32 slot = atomicAdd(&cand_cnt[grow], 1u);
                    if (slot < MAXCAND) cand[(size_t)grow * MAXCAND + slot] = (u16)(col0 + cl);
                }
            }
        }
}

// ------- refine: reproduce the fp32 serial-FMA comparison BIT-EXACTLY ---------
// dv = fp32(rs + es) - 2*acc, acc = ascending-k fp32 fmaf chain. This matches
// the plain fp32 tile-GEMM (R2) and the np reference's fp32 tie-bins.
__global__ __launch_bounds__(256) void refine_gather_kernel(
    const float* __restrict__ lat, const float* __restrict__ emb,
    const float* __restrict__ row_sq, const float* __restrict__ emb_sq,
    const u32* __restrict__ cand_cnt, const u16* __restrict__ cand,
    float* __restrict__ qout, float* __restrict__ indout,
    u32* __restrict__ hist, float* __restrict__ loss_part) {
    __shared__ float xs[4][260];
    __shared__ float lred[4];
    const int wave = threadIdx.x >> 6, lane = threadIdx.x & 63;
    const int row = blockIdx.x * 4 + wave;

    float4 xv = *reinterpret_cast<const float4*>(lat + (size_t)row * DDIM + lane * 4);
    *reinterpret_cast<float4*>(&xs[wave][lane * 4]) = xv;
    __syncthreads();

    int cnt = (int)cand_cnt[row];
    if (cnt > MAXCAND) cnt = MAXCAND;
    int slot = lane & 15;
    if (slot >= cnt) slot = 0;   // cnt >= 1 always (block-min is recorded)
    int c = cand[(size_t)row * MAXCAND + slot];

    // serial ascending-k fp32 FMA chain (bit-exact vs fp32 tile GEMM)
    const float* erow = emb + (size_t)c * DDIM;
    float acc = 0.0f;
    for (int k4 = 0; k4 < 64; ++k4) {
        float4 ev = *reinterpret_cast<const float4*>(erow + k4 * 4);
        float4 xq = *reinterpret_cast<const float4*>(&xs[wave][k4 * 4]);
        acc = __builtin_fmaf(xq.x, ev.x, acc);
        acc = __builtin_fmaf(xq.y, ev.y, acc);
        acc = __builtin_fmaf(xq.z, ev.z, acc);
        acc = __builtin_fmaf(xq.w, ev.w, acc);
    }
    float t = row_sq[row] + emb_sq[c];
    float dv = __builtin_fmaf(-2.0f, acc, t);   // == t - 2*acc exactly (x2 exact)

    // lexicographic (dv, index) min over the wave -> fp32 argmin, first-index tie
#pragma unroll
    for (int m = 32; m >= 1; m >>= 1) {
        float od = __shfl_xor(dv, m, 64);
        int oc = __shfl_xor(c, m, 64);
        if (od < dv || (od == dv && oc < c)) { dv = od; c = oc; }
    }
    int bestc = c;

    // gather + quantized_st + loss partial
    float4 ev = *reinterpret_cast<const float4*>(emb + (size_t)bestc * DDIM + lane * 4);
    float dx = ev.x - xv.x, dy = ev.y - xv.y, dz = ev.z - xv.z, dw = ev.w - xv.w;
    float4 q = make_float4(xv.x + dx, xv.y + dy, xv.z + dz, xv.w + dw);
    *reinterpret_cast<float4*>(qout + (size_t)row * DDIM + lane * 4) = q;
    float s = dx * dx + dy * dy + dz * dz + dw * dw;
#pragma unroll
    for (int m = 32; m >= 1; m >>= 1) s += __shfl_xor(s, m, 64);
    if (lane == 0) {
        lred[wave] = s;
        atomicAdd(&hist[bestc], 1u);
        indout[row] = (float)bestc;
    }
    __syncthreads();
    if (threadIdx.x == 0)
        loss_part[blockIdx.x] = (lred[0] + lred[1]) + (lred[2] + lred[3]);
}

// ---------------- scalars: vq_loss (reduce partials), perplexity ---------------
__global__ __launch_bounds__(1024) void scalar_kernel(
    const u32* __restrict__ hist, const float* __restrict__ loss_part,
    float* __restrict__ out_loss, float* __restrict__ out_perp) {
    __shared__ double lred[16];
    __shared__ float ered[16];
    int t = threadIdx.x;
    double ls = 0.0;
#pragma unroll
    for (int i = 0; i < RG_BLOCKS / 1024; ++i)
        ls += (double)loss_part[t + i * 1024];
    float p = (float)hist[t] / 65536.0f;
    float es = p * logf(p + 1e-10f);
#pragma unroll
    for (int m = 32; m >= 1; m >>= 1) {
        ls += __shfl_xor(ls, m, 64);
        es += __shfl_xor(es, m, 64);
    }
    if ((t & 63) == 0) { lred[t >> 6] = ls; ered[t >> 6] = es; }
    __syncthreads();
    if (t < 64) {
        double lv = (t < 16) ? lred[t] : 0.0;
        float ev = (t < 16) ? ered[t] : 0.0f;
#pragma unroll
        for (int m = 32; m >= 1; m >>= 1) {
            lv += __shfl_xor(lv, m, 64);
            ev += __shfl_xor(ev, m, 64);
        }
        if (t == 0) {
            *out_perp = expf(-ev);
            double ml = lv / (double)((size_t)NROWS * DDIM);
            *out_loss = (float)(ml * 0.25 + ml);  // beta*commit + delta*embed (equal)
        }
    }
}

extern "C" void kernel_launch(void* const* d_in, const int* in_sizes, int n_in,
                              void* d_out, int out_size, void* d_ws, size_t ws_size,
                              hipStream_t stream) {
    const float* lat = (const float*)d_in[0];
    const float* emb = (const float*)d_in[1];
    float* out = (float*)d_out;
    char* ws = (char*)d_ws;

    u32* cand_cnt = (u32*)ws;                          // 65536*4  = 262144 B
    u16* cand = (u16*)(ws + 262144);                   // 65536*16*2 = 2 MB
    float* row_sq = (float*)(ws + 2359296);            // 262144 B
    float* emb_sq = (float*)(ws + 2621440);            // 4096 B
    u32* hist = (u32*)(ws + 2625536);                  // 4096 B
    float* loss_part = (float*)(ws + 2629632);         // 65536 B

    init_kernel<<<256, 256, 0, stream>>>(cand_cnt, hist);
    sqnorm_kernel<<<(NROWS + KCODES) / 4, 256, 0, stream>>>(lat, emb, row_sq, emb_sq);
    dim3 grid(KCODES / 128, NROWS / 128);
    dist_mfma_kernel<<<grid, 256, 0, stream>>>(lat, emb, row_sq, emb_sq,
                                               out + DIST_OFF, cand_cnt, cand);
    refine_gather_kernel<<<RG_BLOCKS, 256, 0, stream>>>(lat, emb, row_sq, emb_sq,
                                                        cand_cnt, cand,
                                                        out + Q_OFF, out + IND_OFF,
                                                        hist, loss_part);
    scalar_kernel<<<1, 1024, 0, stream>>>(hist, loss_part,
                                          out + LOSS_OFF, out + PERP_OFF);
}